// Round 26
// baseline (43.174 us; speedup 1.0000x reference)
//
#include <hip/hip_runtime.h>
#include <hip/hip_cooperative_groups.h>

namespace cg = cooperative_groups;

constexpr int T_DIM       = 16;
constexpr int TOK         = 16384;
constexpr int E_DIM       = 128;
constexpr int N_NODE_C    = 8192;
constexpr int NUM_NODES_C = 50000;
constexpr int COMP_LEN_C  = 64;
constexpr int MAX_LEN_C   = 782;
constexpr int COMP_DIM_C  = 32;
constexpr float EPS_F     = 1e-5f;

constexpr int D2      = COMP_LEN_C * COMP_DIM_C;   // 2048
constexpr int GRID_C  = 1024;                      // 16 t x 64 chunks; 4 blocks/CU
constexpr int BLK_C   = 512;                       // 8 waves/SIMD resident
constexpr int PER_T   = 64;
constexpr int RPB     = 128;                       // rows per block
constexpr int N_SIDX  = COMP_LEN_C * MAX_LEN_C;    // 50048 build entries

// d_ws: W8 (3.2MB, memset) | P partials (8MB, fully overwritten -> no zeroing).
constexpr size_t W8_BYTES = (size_t)NUM_NODES_C * COMP_LEN_C;   // 3,200,000
constexpr size_t P_OFF    = 3211264;                            // 4KB-aligned
// P: [GRID_C][D2] floats = 8 MB

struct SharedT {
  float    vtile[RPB][COMP_DIM_C];  // 16KB
  unsigned atile[RPB][16];          // 8KB
  float    red[16];
};

// ---- Phase A: dense x-stream + LN + pool -> vtile; prefetch node ids.
// 8 lanes/row, 16 elems/lane; 3-level shuffle reduction; b128 vtile write.
// (R21/R25-proven best)
__device__ __forceinline__ void phaseA_stream(
    SharedT& sh, int t, int chunk, const float* __restrict__ x,
    const float* __restrict__ g1, const float* __restrict__ b1,
    const int* __restrict__ node_idx, int* nid4) {
  const int tid = threadIdx.x, lane = tid & 63, wave = tid >> 6;
  const int sl = lane & 7;      // position within row (elems sl*16 .. +15)
  const int rg = lane >> 3;     // row within 8-row iter group
  const int rbase = chunk * RPB;
  const int* nit = node_idx + (size_t)t * N_NODE_C;
  const float4* xv = reinterpret_cast<const float4*>(x + (size_t)t * TOK * E_DIM);

#pragma unroll
  for (int j = 0; j < 4; ++j) nid4[j] = nit[rbase + ((tid + j * 512) >> 4)];

  float4 gq[4];
  float sg[4], sb[4];
#pragma unroll
  for (int k = 0; k < 4; ++k) {
    gq[k] = *reinterpret_cast<const float4*>(g1 + sl * 16 + k * 4);
    float4 bq = *reinterpret_cast<const float4*>(b1 + sl * 16 + k * 4);
    sg[k] = gq[k].x + gq[k].y + gq[k].z + gq[k].w;
    sb[k] = bq.x + bq.y + bq.z + bq.w;
  }

  const int wr0 = rbase + wave * 16;
#pragma unroll
  for (int it = 0; it < 2; ++it) {
    const int row = wr0 + it * 8 + rg;
    float4 xq[4];
#pragma unroll
    for (int k = 0; k < 4; ++k)
      xq[k] = xv[(size_t)row * 32 + sl * 4 + k];   // 64B contiguous per lane

    float s = 0.f, ss = 0.f;
#pragma unroll
    for (int k = 0; k < 4; ++k) {
      s  += (xq[k].x + xq[k].y) + (xq[k].z + xq[k].w);
      ss += xq[k].x * xq[k].x + xq[k].y * xq[k].y
          + xq[k].z * xq[k].z + xq[k].w * xq[k].w;
    }
#pragma unroll
    for (int m = 1; m < 8; m <<= 1) { s += __shfl_xor(s, m); ss += __shfl_xor(ss, m); }
    float mu   = s * (1.0f / E_DIM);
    float rstd = rsqrtf(ss * (1.0f / E_DIM) - mu * mu + EPS_F);

    float4 pv;
    pv.x = (xq[0].x * gq[0].x + xq[0].y * gq[0].y + xq[0].z * gq[0].z + xq[0].w * gq[0].w
            - mu * sg[0]) * rstd + sb[0];
    pv.y = (xq[1].x * gq[1].x + xq[1].y * gq[1].y + xq[1].z * gq[1].z + xq[1].w * gq[1].w
            - mu * sg[1]) * rstd + sb[1];
    pv.z = (xq[2].x * gq[2].x + xq[2].y * gq[2].y + xq[2].z * gq[2].z + xq[2].w * gq[2].w
            - mu * sg[2]) * rstd + sb[2];
    pv.w = (xq[3].x * gq[3].x + xq[3].y * gq[3].y + xq[3].z * gq[3].z + xq[3].w * gq[3].w
            - mu * sg[3]) * rstd + sb[3];
    *reinterpret_cast<float4*>(&sh.vtile[wave * 16 + it * 8 + rg][sl * 4]) = pv;
  }
}

// ---- Phase B: W-gather -> atile; u8 GEMM (2c x 2d @ 512 threads, paired-k);
// flush via PLAIN coalesced stores to this block's partial row (NO atomics).
__device__ __forceinline__ void phaseB_gemmflush(
    SharedT& sh, const unsigned* __restrict__ W32, const int* nid4,
    float* __restrict__ P, int bid) {
  const int tid = threadIdx.x;
  __syncthreads();   // vtile ready (coop: W ordered by grid.sync before this)

  unsigned wg4[4];
#pragma unroll
  for (int j = 0; j < 4; ++j)
    wg4[j] = W32[(size_t)nid4[j] * 16 + ((tid + j * 512) & 15)];
#pragma unroll
  for (int j = 0; j < 4; ++j) {
    int w = tid + j * 512;
    sh.atile[w >> 4][w & 15] = wg4[j];
  }
  __syncthreads();

  const int c2 = tid >> 4, d2 = tid & 15;
  const int aw = c2 >> 1, ash = (c2 & 1) * 16;
  float2 acc0{0,0}, acc1{0,0};
  const float2* vt2 = reinterpret_cast<const float2*>(&sh.vtile[0][0]);
#pragma unroll 2
  for (int k = 0; k < RPB; k += 2) {
    unsigned a4a = sh.atile[k][aw];
    unsigned a4b = sh.atile[k + 1][aw];
    float2 v2a = vt2[k * 16 + d2];
    float2 v2b = vt2[(k + 1) * 16 + d2];
    float a0a = (float)((a4a >> ash) & 255u), a1a = (float)((a4a >> (ash + 8)) & 255u);
    float a0b = (float)((a4b >> ash) & 255u), a1b = (float)((a4b >> (ash + 8)) & 255u);
    acc0.x += a0a * v2a.x; acc0.y += a0a * v2a.y;
    acc1.x += a1a * v2a.x; acc1.y += a1a * v2a.y;
    acc0.x += a0b * v2b.x; acc0.y += a0b * v2b.y;
    acc1.x += a1b * v2b.x; acc1.y += a1b * v2b.y;
  }
  float2* pr2 = reinterpret_cast<float2*>(P + (size_t)bid * D2);
  const int c0 = c2 * 2;
  pr2[(c0 + 0) * 16 + d2] = acc0;   // plain b64 stores, contiguous per 16 threads
  pr2[(c0 + 1) * 16 + d2] = acc1;
}

// ---- Phase C: per t, sum 64 chunk-partials (L2-hot) + final LN2.
// 16 blocks x 512 threads; thread owns 4 output elems.
__device__ __forceinline__ void phaseC_final(
    SharedT& sh, int t, const float* __restrict__ P, const float* __restrict__ g2,
    const float* __restrict__ b2, float* __restrict__ out) {
  const float scale = 1.0f / (4.0f * (float)MAX_LEN_C);
  const int tid = threadIdx.x;
  float4 acc{0,0,0,0};
  const float* base = P + (size_t)t * PER_T * D2 + tid * 4;
#pragma unroll 4
  for (int p = 0; p < PER_T; ++p) {
    float4 v = *reinterpret_cast<const float4*>(base + (size_t)p * D2);
    acc.x += v.x; acc.y += v.y; acc.z += v.z; acc.w += v.w;
  }
  float y[4] = {acc.x * scale, acc.y * scale, acc.z * scale, acc.w * scale};
  float s = 0.f, q = 0.f;
#pragma unroll
  for (int k = 0; k < 4; ++k) { s += y[k]; q += y[k] * y[k]; }
#pragma unroll
  for (int m = 1; m < 64; m <<= 1) { s += __shfl_xor(s, m); q += __shfl_xor(q, m); }
  const int w = tid >> 6, ln = tid & 63;
  if (ln == 0) { sh.red[w] = s; sh.red[8 + w] = q; }
  __syncthreads();
  float ts = 0.f, tq = 0.f;
#pragma unroll
  for (int k = 0; k < 8; ++k) { ts += sh.red[k]; tq += sh.red[8 + k]; }
  float mu = ts * (1.0f / D2);
  float rstd = rsqrtf(tq * (1.0f / D2) - mu * mu + EPS_F);
#pragma unroll
  for (int k = 0; k < 4; ++k) {
    int idx = tid * 4 + k;
    out[(size_t)t * D2 + idx] = (y[k] - mu) * rstd * g2[idx] + b2[idx];
  }
}

// ---- Coop mega: {spread-build ∥ stream} -> sync -> {gather+GEMM+store} -> sync
// -> {reduce+final}.
__global__ __launch_bounds__(512, 8) void mega_kernel(
    const float* __restrict__ x, const float* __restrict__ g1, const float* __restrict__ b1,
    const int* __restrict__ node_idx, const int* __restrict__ sidx,
    const float* __restrict__ g2, const float* __restrict__ b2,
    unsigned* __restrict__ W8w, float* __restrict__ P, float* __restrict__ out) {
  cg::grid_group grid = cg::this_grid();
  __shared__ SharedT sh;
  const int t = blockIdx.x >> 6, chunk = blockIdx.x & 63;

  // Balanced build: every block contributes 49 entries (one atomic per thread).
  {
    int bi = blockIdx.x * 49 + threadIdx.x;
    if (threadIdx.x < 49 && bi < N_SIDX) {
      int c = bi / MAX_LEN_C;
      int n = sidx[bi];
      int byteoff = n * COMP_LEN_C + c;
      atomicAdd(&W8w[byteoff >> 2], 1u << (8 * (byteoff & 3)));
    }
  }
  int nid4[4];
  phaseA_stream(sh, t, chunk, x, g1, b1, node_idx, nid4);
  grid.sync();                       // W built; vtile resident in LDS
  phaseB_gemmflush(sh, (const unsigned*)W8w, nid4, P, blockIdx.x);
  grid.sync();                       // all partials stored
  if (blockIdx.x < T_DIM) phaseC_final(sh, blockIdx.x, P, g2, b2, out);
}

// ---- Fallback (non-coop), identical math, dispatch-ordered.
__global__ void build_w8_kernel(const int* __restrict__ sidx, unsigned* __restrict__ W8w) {
  const int c  = blockIdx.x >> 2;
  const int jc = blockIdx.x & 3;
  const int j  = jc * 196 + threadIdx.x;
  if (j < MAX_LEN_C && threadIdx.x < 196) {
    int n = sidx[c * MAX_LEN_C + j];
    int byteoff = n * COMP_LEN_C + c;
    atomicAdd(&W8w[byteoff >> 2], 1u << (8 * (byteoff & 3)));
  }
}
__global__ __launch_bounds__(512, 8) void main_nc(
    const float* __restrict__ x, const float* __restrict__ g1, const float* __restrict__ b1,
    const int* __restrict__ node_idx, const unsigned* __restrict__ W32,
    float* __restrict__ P) {
  __shared__ SharedT sh;
  const int t = blockIdx.x >> 6, chunk = blockIdx.x & 63;
  int nid4[4];
  phaseA_stream(sh, t, chunk, x, g1, b1, node_idx, nid4);
  phaseB_gemmflush(sh, W32, nid4, P, blockIdx.x);
}
__global__ __launch_bounds__(512) void final_nc(
    const float* __restrict__ P, const float* __restrict__ g2,
    const float* __restrict__ b2, float* __restrict__ out) {
  __shared__ SharedT sh;
  phaseC_final(sh, blockIdx.x, P, g2, b2, out);
}

extern "C" void kernel_launch(void* const* d_in, const int* in_sizes, int n_in,
                              void* d_out, int out_size, void* d_ws, size_t ws_size,
                              hipStream_t stream) {
  const float* x     = (const float*)d_in[0];
  const float* ln1_g = (const float*)d_in[1];
  const float* ln1_b = (const float*)d_in[2];
  const float* ln2_g = (const float*)d_in[3];
  const float* ln2_b = (const float*)d_in[4];
  const int* node_idx = (const int*)d_in[5];
  const int* sidx     = (const int*)d_in[6];
  float* out = (float*)d_out;

  unsigned char* ws = (unsigned char*)d_ws;
  unsigned* W8w = (unsigned*)ws;
  float* P = (float*)(ws + P_OFF);   // 8MB, fully overwritten each call

  hipMemsetAsync(W8w, 0, W8_BYTES, stream);   // W8 only (P needs no zeroing)

  int maxActive = 0;
  hipError_t occ = hipOccupancyMaxActiveBlocksPerMultiprocessor(
      &maxActive, (const void*)mega_kernel, BLK_C, 0);
  bool coop = (occ == hipSuccess) && (maxActive >= 4);   // 1024 blocks / 256 CU

  if (coop) {
    void* args[] = {(void*)&x, (void*)&ln1_g, (void*)&ln1_b, (void*)&node_idx,
                    (void*)&sidx, (void*)&ln2_g, (void*)&ln2_b,
                    (void*)&W8w, (void*)&P, (void*)&out};
    hipError_t e = hipLaunchCooperativeKernel((void*)mega_kernel, dim3(GRID_C),
                                              dim3(BLK_C), args, 0, stream);
    if (e == hipSuccess) return;
  }

  build_w8_kernel<<<COMP_LEN_C * 4, 256, 0, stream>>>(sidx, W8w);
  main_nc<<<GRID_C, BLK_C, 0, stream>>>(x, ln1_g, ln1_b, node_idx,
                                        (const unsigned*)W8w, P);
  final_nc<<<T_DIM, 512, 0, stream>>>(P, ln2_g, ln2_b, out);
}

// Round 27
// 39.466 us; speedup vs baseline: 1.0940x; 1.0940x over previous
//
#include <hip/hip_runtime.h>
#include <hip/hip_cooperative_groups.h>

namespace cg = cooperative_groups;

constexpr int T_DIM       = 16;
constexpr int TOK         = 16384;
constexpr int E_DIM       = 128;
constexpr int N_NODE_C    = 8192;
constexpr int NUM_NODES_C = 50000;
constexpr int COMP_LEN_C  = 64;
constexpr int MAX_LEN_C   = 782;
constexpr int COMP_DIM_C  = 32;
constexpr float EPS_F     = 1e-5f;

constexpr int D2      = COMP_LEN_C * COMP_DIM_C;   // 2048
constexpr int GRID_C  = 1024;                      // 16 t x 64 chunks; 4 blocks/CU
constexpr int BLK_C   = 512;                       // 8 waves/SIMD resident
constexpr int PER_T   = 64;
constexpr int RPB     = 128;                       // rows per block
constexpr int N_SIDX  = COMP_LEN_C * MAX_LEN_C;    // 50048 build entries

// d_ws: W8 (3.2MB) | Agg (128KB). One memset zeroes both (replay-safe).
constexpr size_t W8_BYTES   = (size_t)NUM_NODES_C * COMP_LEN_C;   // 3,200,000
constexpr size_t AGG_OFF    = 3211264;                            // 4KB-aligned
constexpr size_t AGG_BYTES  = (size_t)T_DIM * D2 * sizeof(float); // 131,072
constexpr size_t ZERO_BYTES = AGG_OFF + AGG_BYTES;

struct SharedT {
  float    vtile[RPB][COMP_DIM_C];  // 16KB
  unsigned atile[RPB][16];          // 8KB
  float    red[16];
};

// ---- Phase A: dense x-stream + LN + pool -> vtile; prefetch node ids.
// 8 lanes/row, 16 elems/lane; 3-level shuffle reduction; b128 vtile write.
// (best measured: R21 39.6us / R25 40.0us)
__device__ __forceinline__ void phaseA_stream(
    SharedT& sh, int t, int chunk, const float* __restrict__ x,
    const float* __restrict__ g1, const float* __restrict__ b1,
    const int* __restrict__ node_idx, int* nid4) {
  const int tid = threadIdx.x, lane = tid & 63, wave = tid >> 6;
  const int sl = lane & 7;      // position within row (elems sl*16 .. +15)
  const int rg = lane >> 3;     // row within 8-row iter group
  const int rbase = chunk * RPB;
  const int* nit = node_idx + (size_t)t * N_NODE_C;
  const float4* xv = reinterpret_cast<const float4*>(x + (size_t)t * TOK * E_DIM);

  // 2048 atile words / 512 threads = 4 each; broadcast nid loads first.
#pragma unroll
  for (int j = 0; j < 4; ++j) nid4[j] = nit[rbase + ((tid + j * 512) >> 4)];

  // per-lane LN constants for elems [sl*16, sl*16+16): 4 pool groups
  float4 gq[4];
  float sg[4], sb[4];
#pragma unroll
  for (int k = 0; k < 4; ++k) {
    gq[k] = *reinterpret_cast<const float4*>(g1 + sl * 16 + k * 4);
    float4 bq = *reinterpret_cast<const float4*>(b1 + sl * 16 + k * 4);
    sg[k] = gq[k].x + gq[k].y + gq[k].z + gq[k].w;
    sb[k] = bq.x + bq.y + bq.z + bq.w;
  }

  const int wr0 = rbase + wave * 16;
#pragma unroll
  for (int it = 0; it < 2; ++it) {
    const int row = wr0 + it * 8 + rg;
    float4 xq[4];
#pragma unroll
    for (int k = 0; k < 4; ++k)
      xq[k] = xv[(size_t)row * 32 + sl * 4 + k];   // 64B contiguous per lane

    float s = 0.f, ss = 0.f;
#pragma unroll
    for (int k = 0; k < 4; ++k) {
      s  += (xq[k].x + xq[k].y) + (xq[k].z + xq[k].w);
      ss += xq[k].x * xq[k].x + xq[k].y * xq[k].y
          + xq[k].z * xq[k].z + xq[k].w * xq[k].w;
    }
#pragma unroll
    for (int m = 1; m < 8; m <<= 1) { s += __shfl_xor(s, m); ss += __shfl_xor(ss, m); }
    float mu   = s * (1.0f / E_DIM);
    float rstd = rsqrtf(ss * (1.0f / E_DIM) - mu * mu + EPS_F);

    float4 pv;
    pv.x = (xq[0].x * gq[0].x + xq[0].y * gq[0].y + xq[0].z * gq[0].z + xq[0].w * gq[0].w
            - mu * sg[0]) * rstd + sb[0];
    pv.y = (xq[1].x * gq[1].x + xq[1].y * gq[1].y + xq[1].z * gq[1].z + xq[1].w * gq[1].w
            - mu * sg[1]) * rstd + sb[1];
    pv.z = (xq[2].x * gq[2].x + xq[2].y * gq[2].y + xq[2].z * gq[2].z + xq[2].w * gq[2].w
            - mu * sg[2]) * rstd + sb[2];
    pv.w = (xq[3].x * gq[3].x + xq[3].y * gq[3].y + xq[3].z * gq[3].z + xq[3].w * gq[3].w
            - mu * sg[3]) * rstd + sb[3];
    *reinterpret_cast<float4*>(&sh.vtile[wave * 16 + it * 8 + rg][sl * 4]) = pv;
  }
}

// ---- Phase B: W-gather -> atile; u8 GEMM (2c x 2d per thread @ 512 threads,
// paired-k LDS reads — max wave-parallelism); atomic flush into Agg
// (A/B-proven vs plain-store partials: atomics faster, R25 40.0 vs R26 43.2).
__device__ __forceinline__ void phaseB_gemmflush(
    SharedT& sh, int t, const unsigned* __restrict__ W32, const int* nid4,
    float* __restrict__ Agg) {
  const int tid = threadIdx.x;
  __syncthreads();   // vtile ready (coop: W ordered by grid.sync before this)

  unsigned wg4[4];
#pragma unroll
  for (int j = 0; j < 4; ++j)
    wg4[j] = W32[(size_t)nid4[j] * 16 + ((tid + j * 512) & 15)];
#pragma unroll
  for (int j = 0; j < 4; ++j) {
    int w = tid + j * 512;
    sh.atile[w >> 4][w & 15] = wg4[j];
  }
  __syncthreads();

  const int c2 = tid >> 4, d2 = tid & 15;
  const int aw = c2 >> 1, ash = (c2 & 1) * 16;
  float2 acc0{0,0}, acc1{0,0};
  const float2* vt2 = reinterpret_cast<const float2*>(&sh.vtile[0][0]);
#pragma unroll 2
  for (int k = 0; k < RPB; k += 2) {
    unsigned a4a = sh.atile[k][aw];
    unsigned a4b = sh.atile[k + 1][aw];
    float2 v2a = vt2[k * 16 + d2];
    float2 v2b = vt2[(k + 1) * 16 + d2];
    float a0a = (float)((a4a >> ash) & 255u), a1a = (float)((a4a >> (ash + 8)) & 255u);
    float a0b = (float)((a4b >> ash) & 255u), a1b = (float)((a4b >> (ash + 8)) & 255u);
    acc0.x += a0a * v2a.x; acc0.y += a0a * v2a.y;
    acc1.x += a1a * v2a.x; acc1.y += a1a * v2a.y;
    acc0.x += a0b * v2b.x; acc0.y += a0b * v2b.y;
    acc1.x += a1b * v2b.x; acc1.y += a1b * v2b.y;
  }
  float* aggt = Agg + (size_t)t * D2;
  const int c0 = c2 * 2;
  atomicAdd(&aggt[(c0 + 0) * 32 + d2 * 2],     acc0.x);
  atomicAdd(&aggt[(c0 + 0) * 32 + d2 * 2 + 1], acc0.y);
  atomicAdd(&aggt[(c0 + 1) * 32 + d2 * 2],     acc1.x);
  atomicAdd(&aggt[(c0 + 1) * 32 + d2 * 2 + 1], acc1.y);
}

// ---- Phase C: final LN2 per t (512 threads x 4 elems).
__device__ __forceinline__ void phaseC_final(
    SharedT& sh, int t, const float* __restrict__ Agg, const float* __restrict__ g2,
    const float* __restrict__ b2, float* __restrict__ out) {
  const float scale = 1.0f / (4.0f * (float)MAX_LEN_C);
  const int tid = threadIdx.x;
  float y[4]; float s = 0.f, q = 0.f;
#pragma unroll
  for (int k = 0; k < 4; ++k) {
    float v = Agg[(size_t)t * D2 + tid * 4 + k] * scale;
    y[k] = v; s += v; q += v * v;
  }
#pragma unroll
  for (int m = 1; m < 64; m <<= 1) { s += __shfl_xor(s, m); q += __shfl_xor(q, m); }
  const int w = tid >> 6, ln = tid & 63;
  if (ln == 0) { sh.red[w] = s; sh.red[8 + w] = q; }
  __syncthreads();
  float ts = 0.f, tq = 0.f;
#pragma unroll
  for (int k = 0; k < 8; ++k) { ts += sh.red[k]; tq += sh.red[8 + k]; }
  float mu = ts * (1.0f / D2);
  float rstd = rsqrtf(tq * (1.0f / D2) - mu * mu + EPS_F);
#pragma unroll
  for (int k = 0; k < 4; ++k) {
    int idx = tid * 4 + k;
    out[(size_t)t * D2 + idx] = (y[k] - mu) * rstd * g2[idx] + b2[idx];
  }
}

// ---- Coop mega: {spread-build ∥ stream} -> sync -> {gather+GEMM+flush} -> sync -> final.
__global__ __launch_bounds__(512, 8) void mega_kernel(
    const float* __restrict__ x, const float* __restrict__ g1, const float* __restrict__ b1,
    const int* __restrict__ node_idx, const int* __restrict__ sidx,
    const float* __restrict__ g2, const float* __restrict__ b2,
    unsigned* __restrict__ W8w, float* __restrict__ Agg, float* __restrict__ out) {
  cg::grid_group grid = cg::this_grid();
  __shared__ SharedT sh;
  const int t = blockIdx.x >> 6, chunk = blockIdx.x & 63;

  // Balanced build: every block contributes 49 entries (one atomic per thread).
  {
    int bi = blockIdx.x * 49 + threadIdx.x;
    if (threadIdx.x < 49 && bi < N_SIDX) {
      int c = bi / MAX_LEN_C;
      int n = sidx[bi];
      int byteoff = n * COMP_LEN_C + c;
      atomicAdd(&W8w[byteoff >> 2], 1u << (8 * (byteoff & 3)));
    }
  }
  int nid4[4];
  phaseA_stream(sh, t, chunk, x, g1, b1, node_idx, nid4);
  grid.sync();                       // W built; vtile resident in LDS
  phaseB_gemmflush(sh, t, (const unsigned*)W8w, nid4, Agg);
  grid.sync();                       // Agg complete
  if (blockIdx.x < T_DIM) phaseC_final(sh, blockIdx.x, Agg, g2, b2, out);
}

// ---- Fallback (non-coop), identical math, dispatch-ordered.
__global__ void build_w8_kernel(const int* __restrict__ sidx, unsigned* __restrict__ W8w) {
  const int c  = blockIdx.x >> 2;
  const int jc = blockIdx.x & 3;
  const int j  = jc * 196 + threadIdx.x;
  if (j < MAX_LEN_C && threadIdx.x < 196) {
    int n = sidx[c * MAX_LEN_C + j];
    int byteoff = n * COMP_LEN_C + c;
    atomicAdd(&W8w[byteoff >> 2], 1u << (8 * (byteoff & 3)));
  }
}
__global__ __launch_bounds__(512, 8) void main_nc(
    const float* __restrict__ x, const float* __restrict__ g1, const float* __restrict__ b1,
    const int* __restrict__ node_idx, const unsigned* __restrict__ W32,
    float* __restrict__ Agg) {
  __shared__ SharedT sh;
  const int t = blockIdx.x >> 6, chunk = blockIdx.x & 63;
  int nid4[4];
  phaseA_stream(sh, t, chunk, x, g1, b1, node_idx, nid4);
  phaseB_gemmflush(sh, t, W32, nid4, Agg);
}
__global__ __launch_bounds__(512) void final_nc(
    const float* __restrict__ Agg, const float* __restrict__ g2,
    const float* __restrict__ b2, float* __restrict__ out) {
  __shared__ SharedT sh;
  phaseC_final(sh, blockIdx.x, Agg, g2, b2, out);
}

extern "C" void kernel_launch(void* const* d_in, const int* in_sizes, int n_in,
                              void* d_out, int out_size, void* d_ws, size_t ws_size,
                              hipStream_t stream) {
  const float* x     = (const float*)d_in[0];
  const float* ln1_g = (const float*)d_in[1];
  const float* ln1_b = (const float*)d_in[2];
  const float* ln2_g = (const float*)d_in[3];
  const float* ln2_b = (const float*)d_in[4];
  const int* node_idx = (const int*)d_in[5];
  const int* sidx     = (const int*)d_in[6];
  float* out = (float*)d_out;

  unsigned char* ws = (unsigned char*)d_ws;
  unsigned* W8w = (unsigned*)ws;
  float* Agg = (float*)(ws + AGG_OFF);

  hipMemsetAsync(ws, 0, ZERO_BYTES, stream);   // W8 + Agg (replay-safe)

  int maxActive = 0;
  hipError_t occ = hipOccupancyMaxActiveBlocksPerMultiprocessor(
      &maxActive, (const void*)mega_kernel, BLK_C, 0);
  bool coop = (occ == hipSuccess) && (maxActive >= 4);   // 1024 blocks / 256 CU

  if (coop) {
    void* args[] = {(void*)&x, (void*)&ln1_g, (void*)&ln1_b, (void*)&node_idx,
                    (void*)&sidx, (void*)&ln2_g, (void*)&ln2_b,
                    (void*)&W8w, (void*)&Agg, (void*)&out};
    hipError_t e = hipLaunchCooperativeKernel((void*)mega_kernel, dim3(GRID_C),
                                              dim3(BLK_C), args, 0, stream);
    if (e == hipSuccess) return;
  }

  build_w8_kernel<<<COMP_LEN_C * 4, 256, 0, stream>>>(sidx, W8w);
  main_nc<<<GRID_C, BLK_C, 0, stream>>>(x, ln1_g, ln1_b, node_idx,
                                        (const unsigned*)W8w, Agg);
  final_nc<<<T_DIM, 512, 0, stream>>>(Agg, ln2_g, ln2_b, out);
}